// Round 1
// baseline (803.194 us; speedup 1.0000x reference)
//
#include <hip/hip_runtime.h>

#define HH 256
#define WW 256
#define CC 16
#define BB 8
#define HID 128
#define HW (HH*WW)
#define CHW (CC*HH*WW)

__device__ __forceinline__ float ldz(const float* __restrict__ p, int h, int w) {
    return (h >= 0 && h < HH && w >= 0 && w < WW) ? p[h * WW + w] : 0.0f;
}

// Per-step heavy kernel: perceive (identity + 2 depthwise sobel) + per-pixel MLP.
// Also writes the "pre" life mask (maxpool3(x[:,3]) > 0.1).
__global__ __launch_bounds__(256) void ca_step_mlp(
    const float* __restrict__ x,      // [B,C,H,W]
    const float* __restrict__ fc0w,   // [128,48]
    const float* __restrict__ fc0b,   // [128]
    const float* __restrict__ fc1wT,  // [128,16]  (transposed fc1_w)
    const float* __restrict__ mask,   // [B,H,W] for this step
    float* __restrict__ xn,           // [B,C,H,W]
    float* __restrict__ pre)          // [B,H,W]
{
    const int tid = threadIdx.x;
    const int w = blockIdx.x * 64 + (tid & 63);
    const int h = blockIdx.y * 4 + (tid >> 6);
    const int b = blockIdx.z;
    const float* __restrict__ xb = x + (size_t)b * CHW;

    float y[48];
    #pragma unroll
    for (int c = 0; c < CC; ++c) {
        const float* __restrict__ pc = xb + c * HW;
        float v00 = ldz(pc, h - 1, w - 1), v01 = ldz(pc, h - 1, w), v02 = ldz(pc, h - 1, w + 1);
        float v10 = ldz(pc, h,     w - 1), v11 = pc[h * WW + w],    v12 = ldz(pc, h,     w + 1);
        float v20 = ldz(pc, h + 1, w - 1), v21 = ldz(pc, h + 1, w), v22 = ldz(pc, h + 1, w + 1);
        y[c]      = v11;
        y[16 + c] = ((v02 - v00) + 2.0f * (v12 - v10) + (v22 - v20)) * 0.125f;
        y[32 + c] = ((v20 - v00) + 2.0f * (v21 - v01) + (v22 - v02)) * 0.125f;
        if (c == 3) {
            // zero-padded max is equivalent to -inf-padded max for the >0.1 test
            float m = fmaxf(fmaxf(fmaxf(v00, v01), fmaxf(v02, v10)),
                            fmaxf(fmaxf(v11, v12), fmaxf(fmaxf(v20, v21), v22)));
            pre[((size_t)b * HH + h) * WW + w] = (m > 0.1f) ? 1.0f : 0.0f;
        }
    }

    float acc[16];
    #pragma unroll
    for (int c = 0; c < 16; ++c) acc[c] = 0.0f;

    // MLP: weights are wave-uniform -> scalar loads; all math stays v_fmac_f32
    #pragma unroll 2
    for (int k = 0; k < HID; ++k) {
        const float* __restrict__ wr = fc0w + k * 48;
        float h0 = 0.f, h1 = 0.f, h2 = 0.f, h3 = 0.f;
        #pragma unroll
        for (int c = 0; c < 48; c += 4) {
            h0 += wr[c]     * y[c];
            h1 += wr[c + 1] * y[c + 1];
            h2 += wr[c + 2] * y[c + 2];
            h3 += wr[c + 3] * y[c + 3];
        }
        float hk = fmaxf((h0 + h1) + (h2 + h3) + fc0b[k], 0.0f);
        const float* __restrict__ w1 = fc1wT + k * 16;
        #pragma unroll
        for (int c = 0; c < 16; ++c) acc[c] += w1[c] * hk;
    }

    const float mk = mask[((size_t)b * HH + h) * WW + w];
    float* __restrict__ xnb = xn + (size_t)b * CHW;
    const size_t pix = (size_t)h * WW + w;
    #pragma unroll
    for (int c = 0; c < 16; ++c) {
        xnb[c * HW + pix] = y[c] + acc[c] * mk;  // y[c] is the center value of channel c
    }
}

// Per-step life kernel: post = maxpool3(xn[:,3]) > 0.1; out = xn * (pre & post)
__global__ __launch_bounds__(256) void ca_step_life(
    const float* __restrict__ xn,
    const float* __restrict__ pre,
    float* __restrict__ xout)
{
    const int tid = threadIdx.x;
    const int w = blockIdx.x * 64 + (tid & 63);
    const int h = blockIdx.y * 4 + (tid >> 6);
    const int b = blockIdx.z;
    const float* __restrict__ alpha = xn + ((size_t)b * CC + 3) * HW;

    float m = fmaxf(fmaxf(fmaxf(ldz(alpha, h - 1, w - 1), ldz(alpha, h - 1, w)),
                          fmaxf(ldz(alpha, h - 1, w + 1), ldz(alpha, h, w - 1))),
                    fmaxf(fmaxf(alpha[h * WW + w], ldz(alpha, h, w + 1)),
                          fmaxf(fmaxf(ldz(alpha, h + 1, w - 1), ldz(alpha, h + 1, w)),
                                ldz(alpha, h + 1, w + 1))));
    const float prev = pre[((size_t)b * HH + h) * WW + w];
    const float life = (m > 0.1f && prev > 0.5f) ? 1.0f : 0.0f;

    const float* __restrict__ xnb = xn + (size_t)b * CHW;
    float* __restrict__ xob = xout + (size_t)b * CHW;
    const size_t pix = (size_t)h * WW + w;
    #pragma unroll
    for (int c = 0; c < 16; ++c) xob[c * HW + pix] = xnb[c * HW + pix] * life;
}

__global__ void transpose_fc1(const float* __restrict__ fc1w, float* __restrict__ fc1wT) {
    int i = blockIdx.x * 256 + threadIdx.x;
    if (i < CC * HID) {
        int c = i >> 7;        // 0..15
        int k = i & (HID - 1); // 0..127
        fc1wT[k * 16 + c] = fc1w[i];
    }
}

extern "C" void kernel_launch(void* const* d_in, const int* in_sizes, int n_in,
                              void* d_out, int out_size, void* d_ws, size_t ws_size,
                              hipStream_t stream) {
    const float* x      = (const float*)d_in[0];  // [8,16,256,256]
    const float* fc0w   = (const float*)d_in[1];  // [128,48]
    const float* fc0b   = (const float*)d_in[2];  // [128]
    const float* fc1w   = (const float*)d_in[3];  // [16,128]
    const float* stoch  = (const float*)d_in[4];  // [4,8,1,256,256]
    float* out = (float*)d_out;

    float* ws     = (float*)d_ws;
    float* xn     = ws;                         // 8388608 floats
    float* xtmp   = ws + (size_t)BB * CHW;      // 8388608 floats
    float* pre    = xtmp + (size_t)BB * CHW;    // 524288 floats
    float* fc1wT  = pre + (size_t)BB * HW;      // 2048 floats

    transpose_fc1<<<8, 256, 0, stream>>>(fc1w, fc1wT);

    dim3 block(256);
    dim3 grid(WW / 64, HH / 4, BB);

    for (int s = 0; s < 4; ++s) {
        const float* xin = (s == 0) ? x : xtmp;
        const float* msk = stoch + (size_t)s * BB * HW;
        ca_step_mlp<<<grid, block, 0, stream>>>(xin, fc0w, fc0b, fc1wT, msk, xn, pre);
        float* xo = (s == 3) ? out : xtmp;
        ca_step_life<<<grid, block, 0, stream>>>(xn, pre, xo);
    }
}

// Round 4
// 789.710 us; speedup vs baseline: 1.0171x; 1.0171x over previous
//
#include <hip/hip_runtime.h>

#define HH 256
#define WW 256
#define CC 16
#define BB 8
#define HID 128
#define HW (HH*WW)
#define CHW (CC*HH*WW)

__device__ __forceinline__ float ldz(const float* __restrict__ p, int h, int w) {
    return (h >= 0 && h < HH && w >= 0 && w < WW) ? p[h * WW + w] : 0.0f;
}

// Per-step heavy kernel: perceive (identity + 2 depthwise sobel) + per-pixel MLP.
// Each thread computes TWO vertically-adjacent pixels so every scalar-loaded
// weight row feeds 2x the FMAs (cuts the per-iteration lgkmcnt stall fraction).
// Also writes the "pre" life mask (maxpool3(x[:,3]) > 0.1) for both rows.
__global__ __launch_bounds__(256, 3) void ca_step_mlp(
    const float* __restrict__ x,      // [B,C,H,W]
    const float* __restrict__ fc0w,   // [128,48]
    const float* __restrict__ fc0b,   // [128]
    const float* __restrict__ fc1wT,  // [128,16]  (transposed fc1_w)
    const float* __restrict__ mask,   // [B,H,W] for this step
    float* __restrict__ xn,           // [B,C,H,W]
    float* __restrict__ pre)          // [B,H,W]
{
    const int tid = threadIdx.x;
    const int w  = blockIdx.x * 64 + (tid & 63);
    const int h0 = blockIdx.y * 8 + (tid >> 6) * 2;   // this thread: rows h0, h0+1
    const int b  = blockIdx.z;
    const float* __restrict__ xb = x + (size_t)b * CHW;

    float ya[48], yb[48];
    {
        float rowm[4];
        #pragma unroll
        for (int c = 0; c < CC; ++c) {
            const float* __restrict__ pc = xb + c * HW;
            float rs[4], hx[4];
            #pragma unroll
            for (int r = 0; r < 4; ++r) {
                const int hh = h0 - 1 + r;
                float l = ldz(pc, hh, w - 1);
                float m = ldz(pc, hh, w);
                float rr = ldz(pc, hh, w + 1);
                rs[r] = 2.0f * m + (l + rr);   // row sum (1,2,1)
                hx[r] = rr - l;                // row diff (-1,0,1)
                if (r == 1) ya[c] = m;
                if (r == 2) yb[c] = m;
                if (c == 3) rowm[r] = fmaxf(fmaxf(l, m), rr);
            }
            ya[16 + c] = (hx[0] + 2.0f * hx[1] + hx[2]) * 0.125f;
            yb[16 + c] = (hx[1] + 2.0f * hx[2] + hx[3]) * 0.125f;
            ya[32 + c] = (rs[2] - rs[0]) * 0.125f;
            yb[32 + c] = (rs[3] - rs[1]) * 0.125f;
            if (c == 3) {
                // zero-padded max == -inf-padded max for the >0.1 test
                float m0 = fmaxf(fmaxf(rowm[0], rowm[1]), rowm[2]);
                float m1 = fmaxf(fmaxf(rowm[1], rowm[2]), rowm[3]);
                const size_t base = ((size_t)b * HH + h0) * WW + w;
                pre[base]      = (m0 > 0.1f) ? 1.0f : 0.0f;
                pre[base + WW] = (m1 > 0.1f) ? 1.0f : 0.0f;
            }
        }
    }

    float acca[16], accb[16];
    #pragma unroll
    for (int c = 0; c < 16; ++c) { acca[c] = 0.0f; accb[c] = 0.0f; }

    // MLP: weights are wave-uniform -> scalar loads; 128 FMAs per 64 scalar floats
    #pragma unroll 2
    for (int k = 0; k < HID; ++k) {
        const float* __restrict__ wr = fc0w + k * 48;
        float a0 = 0.f, a1 = 0.f, a2 = 0.f, a3 = 0.f;
        float b0 = 0.f, b1 = 0.f, b2 = 0.f, b3 = 0.f;
        #pragma unroll
        for (int c = 0; c < 48; c += 4) {
            const float w0 = wr[c], w1 = wr[c + 1], w2 = wr[c + 2], w3 = wr[c + 3];
            a0 += w0 * ya[c];     b0 += w0 * yb[c];
            a1 += w1 * ya[c + 1]; b1 += w1 * yb[c + 1];
            a2 += w2 * ya[c + 2]; b2 += w2 * yb[c + 2];
            a3 += w3 * ya[c + 3]; b3 += w3 * yb[c + 3];
        }
        const float bias = fc0b[k];
        float ha = fmaxf((a0 + a1) + (a2 + a3) + bias, 0.0f);
        float hb = fmaxf((b0 + b1) + (b2 + b3) + bias, 0.0f);
        const float* __restrict__ w1p = fc1wT + k * 16;
        #pragma unroll
        for (int c = 0; c < 16; ++c) {
            const float wv = w1p[c];
            acca[c] += wv * ha;
            accb[c] += wv * hb;
        }
    }

    const size_t mbase = ((size_t)b * HH + h0) * WW + w;
    const float mk0 = mask[mbase];
    const float mk1 = mask[mbase + WW];
    float* __restrict__ xnb = xn + (size_t)b * CHW;
    const size_t pix = (size_t)h0 * WW + w;
    #pragma unroll
    for (int c = 0; c < 16; ++c) {
        xnb[c * HW + pix]      = ya[c] + acca[c] * mk0;
        xnb[c * HW + pix + WW] = yb[c] + accb[c] * mk1;
    }
}

// Per-step life kernel: post = maxpool3(xn[:,3]) > 0.1; out = xn * (pre & post)
__global__ __launch_bounds__(256) void ca_step_life(
    const float* __restrict__ xn,
    const float* __restrict__ pre,
    float* __restrict__ xout)
{
    const int tid = threadIdx.x;
    const int w = blockIdx.x * 64 + (tid & 63);
    const int h = blockIdx.y * 4 + (tid >> 6);
    const int b = blockIdx.z;
    const float* __restrict__ alpha = xn + ((size_t)b * CC + 3) * HW;

    float m = fmaxf(fmaxf(fmaxf(ldz(alpha, h - 1, w - 1), ldz(alpha, h - 1, w)),
                          fmaxf(ldz(alpha, h - 1, w + 1), ldz(alpha, h, w - 1))),
                    fmaxf(fmaxf(alpha[h * WW + w], ldz(alpha, h, w + 1)),
                          fmaxf(fmaxf(ldz(alpha, h + 1, w - 1), ldz(alpha, h + 1, w)),
                                ldz(alpha, h + 1, w + 1))));
    const float prev = pre[((size_t)b * HH + h) * WW + w];
    const float life = (m > 0.1f && prev > 0.5f) ? 1.0f : 0.0f;

    const float* __restrict__ xnb = xn + (size_t)b * CHW;
    float* __restrict__ xob = xout + (size_t)b * CHW;
    const size_t pix = (size_t)h * WW + w;
    #pragma unroll
    for (int c = 0; c < 16; ++c) xob[c * HW + pix] = xnb[c * HW + pix] * life;
}

__global__ void transpose_fc1(const float* __restrict__ fc1w, float* __restrict__ fc1wT) {
    int i = blockIdx.x * 256 + threadIdx.x;
    if (i < CC * HID) {
        int c = i >> 7;        // 0..15
        int k = i & (HID - 1); // 0..127
        fc1wT[k * 16 + c] = fc1w[i];
    }
}

extern "C" void kernel_launch(void* const* d_in, const int* in_sizes, int n_in,
                              void* d_out, int out_size, void* d_ws, size_t ws_size,
                              hipStream_t stream) {
    const float* x      = (const float*)d_in[0];  // [8,16,256,256]
    const float* fc0w   = (const float*)d_in[1];  // [128,48]
    const float* fc0b   = (const float*)d_in[2];  // [128]
    const float* fc1w   = (const float*)d_in[3];  // [16,128]
    const float* stoch  = (const float*)d_in[4];  // [4,8,1,256,256]
    float* out = (float*)d_out;

    float* ws     = (float*)d_ws;
    float* xn     = ws;                         // 8388608 floats
    float* xtmp   = ws + (size_t)BB * CHW;      // 8388608 floats
    float* pre    = xtmp + (size_t)BB * CHW;    // 524288 floats
    float* fc1wT  = pre + (size_t)BB * HW;      // 2048 floats

    transpose_fc1<<<8, 256, 0, stream>>>(fc1w, fc1wT);

    dim3 block(256);
    dim3 gridM(WW / 64, HH / 8, BB);
    dim3 gridL(WW / 64, HH / 4, BB);

    for (int s = 0; s < 4; ++s) {
        const float* xin = (s == 0) ? x : xtmp;
        const float* msk = stoch + (size_t)s * BB * HW;
        ca_step_mlp<<<gridM, block, 0, stream>>>(xin, fc0w, fc0b, fc1wT, msk, xn, pre);
        float* xo = (s == 3) ? out : xtmp;
        ca_step_life<<<gridL, block, 0, stream>>>(xn, pre, xo);
    }
}